// Round 15
// baseline (119.183 us; speedup 1.0000x reference)
//
#include <hip/hip_runtime.h>
#include <math.h>

#define NN 2048
#define DD 64
#define HH 64

// ---------------------------------------------------------------------------
// Stage 1: u[i][h] = z[i]·Wa[h] + b1[h];  vt[h][j] = z[j]·Wb[h]  (transposed!)
// Plus fused rank-1 terms: a[i] = 0.5*sum_h W2[h]*u[i][h], b[j] likewise on v.
// (unchanged — passing since r9/r13)
// ---------------------------------------------------------------------------
__global__ __launch_bounds__(256) void prep_kernel(
    const float* __restrict__ z, const float* __restrict__ W1,
    const float* __restrict__ b1, const float* __restrict__ W2,
    float* __restrict__ u, float* __restrict__ vt,
    float* __restrict__ a, float* __restrict__ b) {
  __shared__ float zs[8 * DD];
  const int t = threadIdx.x;
  const int i0 = blockIdx.x * 8;
  if (t < 128) {
    reinterpret_cast<float4*>(zs)[t] =
        reinterpret_cast<const float4*>(z + (size_t)i0 * DD)[t];
  }
  __syncthreads();

  const int hs = t & 127;
  const int rg = t >> 7;
  const int h = hs & 63;
  const int side = hs >> 6;
  const float* wrow = W1 + h * (2 * DD) + side * DD;

  float acc0 = 0.f, acc1 = 0.f, acc2 = 0.f, acc3 = 0.f;
#pragma unroll
  for (int d4 = 0; d4 < DD / 4; ++d4) {
    const float4 wv = reinterpret_cast<const float4*>(wrow)[d4];
    const float* z0 = zs + (rg * 4 + 0) * DD + d4 * 4;
    const float* z1 = z0 + DD;
    const float* z2 = z1 + DD;
    const float* z3 = z2 + DD;
    acc0 = fmaf(z0[3], wv.w, fmaf(z0[2], wv.z, fmaf(z0[1], wv.y, fmaf(z0[0], wv.x, acc0))));
    acc1 = fmaf(z1[3], wv.w, fmaf(z1[2], wv.z, fmaf(z1[1], wv.y, fmaf(z1[0], wv.x, acc1))));
    acc2 = fmaf(z2[3], wv.w, fmaf(z2[2], wv.z, fmaf(z2[1], wv.y, fmaf(z2[0], wv.x, acc2))));
    acc3 = fmaf(z3[3], wv.w, fmaf(z3[2], wv.z, fmaf(z3[1], wv.y, fmaf(z3[0], wv.x, acc3))));
  }
  const float bias = side ? 0.0f : b1[h];
  const float s0 = acc0 + bias, s1 = acc1 + bias, s2 = acc2 + bias, s3 = acc3 + bias;
  const int ib = i0 + rg * 4;
  if (side) {
    float* vrow = vt + (size_t)h * NN + ib;  // transposed layout [h][j]
    vrow[0] = s0; vrow[1] = s1; vrow[2] = s2; vrow[3] = s3;
  } else {
    u[(size_t)(ib + 0) * HH + h] = s0;
    u[(size_t)(ib + 1) * HH + h] = s1;
    u[(size_t)(ib + 2) * HH + h] = s2;
    u[(size_t)(ib + 3) * HH + h] = s3;
  }

  const float wh = W2[h];
  float r0 = wh * s0, r1 = wh * s1, r2 = wh * s2, r3 = wh * s3;
#pragma unroll
  for (int m = 1; m < 64; m <<= 1) {
    r0 += __shfl_xor(r0, m);
    r1 += __shfl_xor(r1, m);
    r2 += __shfl_xor(r2, m);
    r3 += __shfl_xor(r3, m);
  }
  if ((t & 63) == 0) {
    float* d2 = side ? b : a;
    d2[ib + 0] = 0.5f * r0;
    d2[ib + 1] = 0.5f * r1;
    d2[ib + 2] = 0.5f * r2;
    d2[ib + 3] = 0.5f * r3;
  }
}

// ---------------------------------------------------------------------------
// Stage 2 (design F): out[i][j] = sigmoid(a[i]+b[j]+b2
//                                  + 0.5*sum_h W2[h]*|u[i,h]+vt[h,j]|), diag 0.
// Flip of E: lane = output row i (u row per-lane contiguous, 16x b128 loads,
// 16KB/wave aggregate-coalesced); the wave's 8 j-columns come from vt at
// BLOCK-UNIFORM addresses -> scalar-pipe s_loads (or 1-line L1-hot VMEM).
// No readlane, no LDS, no barriers. ~1100 instr/lane (vs 2900 in E2).
// VGPR ~48 -> __launch_bounds__(256,8); grid 2048 blocks = 8 waves/SIMD.
// Per-block working set: u 16KB + vt 8KB = L1-resident.
// ---------------------------------------------------------------------------
__global__ __launch_bounds__(256, 8) void pair_kernel(
    const float* __restrict__ u, const float* __restrict__ vt,
    const float* __restrict__ a, const float* __restrict__ b,
    const float* __restrict__ W2, const float* __restrict__ b2,
    float* __restrict__ out) {
  const int t = threadIdx.x;
  const int L = t & 63;                     // lane -> output row
  const int w = t >> 6;                     // wave 0..3
  const int i = blockIdx.y * 64 + L;        // lane's row
  const int j0 = blockIdx.x * 32 + w * 8;   // wave's 8 j-columns (uniform)

  const float* urow = u + (size_t)i * HH;

  float acc[8] = {};
#pragma unroll
  for (int hc = 0; hc < 4; ++hc) {          // 4 chunks of 16 h
    float u16[16];
#pragma unroll
    for (int q = 0; q < 4; ++q) {           // 4x b128: lane-contiguous u row
      const float4 f = *reinterpret_cast<const float4*>(urow + hc * 16 + q * 4);
      u16[q * 4 + 0] = f.x; u16[q * 4 + 1] = f.y;
      u16[q * 4 + 2] = f.z; u16[q * 4 + 3] = f.w;
    }
#pragma unroll
    for (int hh = 0; hh < 16; ++hh) {
      const int h = hc * 16 + hh;
      const float uh = u16[hh];             // static index (unrolled)
      const float wh = W2[h];               // uniform -> s_load
      const float* vr = vt + (size_t)h * NN + j0;  // block-uniform row chunk
#pragma unroll
      for (int c = 0; c < 8; ++c) {
        acc[c] = fmaf(wh, fabsf(uh + vr[c]), acc[c]);  // add + fma(|.|)
      }
    }
  }

  const float ai = a[i] + b2[0];
  float r[8];
#pragma unroll
  for (int c = 0; c < 8; ++c) {
    const float x = ai + b[j0 + c] + 0.5f * acc[c];   // b: uniform s_load
    r[c] = 1.0f / (1.0f + __expf(-x));
    if (i == j0 + c) r[c] = 0.0f;
  }
  float* orow = out + (size_t)i * NN + j0;
  *reinterpret_cast<float4*>(orow) = make_float4(r[0], r[1], r[2], r[3]);
  *reinterpret_cast<float4*>(orow + 4) = make_float4(r[4], r[5], r[6], r[7]);
}

extern "C" void kernel_launch(void* const* d_in, const int* in_sizes, int n_in,
                              void* d_out, int out_size, void* d_ws, size_t ws_size,
                              hipStream_t stream) {
  const float* z  = (const float*)d_in[0];
  const float* W1 = (const float*)d_in[1];
  const float* b1 = (const float*)d_in[2];
  const float* W2 = (const float*)d_in[3];
  const float* b2 = (const float*)d_in[4];
  float* out = (float*)d_out;

  float* u  = (float*)d_ws;               // [2048][64]  512 KB
  float* vt = u + (size_t)NN * HH;        // [64][2048]  512 KB (transposed)
  float* a  = vt + (size_t)NN * HH;       // [2048]      8 KB
  float* b  = a + NN;                     // [2048]      8 KB

  prep_kernel<<<NN / 8, 256, 0, stream>>>(z, W1, b1, W2, u, vt, a, b);
  pair_kernel<<<dim3(NN / 32, NN / 64), 256, 0, stream>>>(u, vt, a, b, W2, b2, out);
}

// Round 16
// 93.900 us; speedup vs baseline: 1.2693x; 1.2693x over previous
//
#include <hip/hip_runtime.h>
#include <math.h>

#define NN 2048
#define DD 64
#define HH 64

// ---------------------------------------------------------------------------
// Stage 1: ut[h][i] = z[i]·Wa[h] + b1[h];  vt[h][j] = z[j]·Wb[h]  (BOTH transposed)
// Plus fused rank-1 terms: a[i] = 0.5*sum_h W2[h]*u[i][h], b[j] likewise on v.
// ---------------------------------------------------------------------------
__global__ __launch_bounds__(256) void prep_kernel(
    const float* __restrict__ z, const float* __restrict__ W1,
    const float* __restrict__ b1, const float* __restrict__ W2,
    float* __restrict__ ut, float* __restrict__ vt,
    float* __restrict__ a, float* __restrict__ b) {
  __shared__ float zs[8 * DD];
  const int t = threadIdx.x;
  const int i0 = blockIdx.x * 8;
  if (t < 128) {
    reinterpret_cast<float4*>(zs)[t] =
        reinterpret_cast<const float4*>(z + (size_t)i0 * DD)[t];
  }
  __syncthreads();

  const int hs = t & 127;
  const int rg = t >> 7;
  const int h = hs & 63;
  const int side = hs >> 6;
  const float* wrow = W1 + h * (2 * DD) + side * DD;

  float acc0 = 0.f, acc1 = 0.f, acc2 = 0.f, acc3 = 0.f;
#pragma unroll
  for (int d4 = 0; d4 < DD / 4; ++d4) {
    const float4 wv = reinterpret_cast<const float4*>(wrow)[d4];
    const float* z0 = zs + (rg * 4 + 0) * DD + d4 * 4;
    const float* z1 = z0 + DD;
    const float* z2 = z1 + DD;
    const float* z3 = z2 + DD;
    acc0 = fmaf(z0[3], wv.w, fmaf(z0[2], wv.z, fmaf(z0[1], wv.y, fmaf(z0[0], wv.x, acc0))));
    acc1 = fmaf(z1[3], wv.w, fmaf(z1[2], wv.z, fmaf(z1[1], wv.y, fmaf(z1[0], wv.x, acc1))));
    acc2 = fmaf(z2[3], wv.w, fmaf(z2[2], wv.z, fmaf(z2[1], wv.y, fmaf(z2[0], wv.x, acc2))));
    acc3 = fmaf(z3[3], wv.w, fmaf(z3[2], wv.z, fmaf(z3[1], wv.y, fmaf(z3[0], wv.x, acc3))));
  }
  const float bias = side ? 0.0f : b1[h];
  const float s0 = acc0 + bias, s1 = acc1 + bias, s2 = acc2 + bias, s3 = acc3 + bias;
  const int ib = i0 + rg * 4;
  {
    float* drow = (side ? vt : ut) + (size_t)h * NN + ib;  // transposed [h][i]
    drow[0] = s0; drow[1] = s1; drow[2] = s2; drow[3] = s3;
  }

  const float wh = W2[h];
  float r0 = wh * s0, r1 = wh * s1, r2 = wh * s2, r3 = wh * s3;
#pragma unroll
  for (int m = 1; m < 64; m <<= 1) {
    r0 += __shfl_xor(r0, m);
    r1 += __shfl_xor(r1, m);
    r2 += __shfl_xor(r2, m);
    r3 += __shfl_xor(r3, m);
  }
  if ((t & 63) == 0) {
    float* d2 = side ? b : a;
    d2[ib + 0] = 0.5f * r0;
    d2[ib + 1] = 0.5f * r1;
    d2[ib + 2] = 0.5f * r2;
    d2[ib + 3] = 0.5f * r3;
  }
}

// ---------------------------------------------------------------------------
// Stage 2 (design G): out[i][j] = sigmoid(a[i]+b[j]+b2
//                                  + 0.5*sum_h W2[h]*|u[i,h]+v[j,h]|), diag 0.
// lane = output row i; u via COALESCED b32 loads from ut[h][i0+L] (16-deep
// independent batches); wave's 8 j-cols via readfirstlane-forced UNIFORM base
// -> genuine s_load on the scalar pipe (vt slice 8KB, K$-resident).
// No readlane, no LDS, no barriers, no per-lane VMEM broadcasts.
// ~1135 vector instrs/lane; VGPR ~45 under __launch_bounds__(256,8)
// -> 8 waves/SIMD; grid (64,32)=2048 blocks = 8 blocks/CU.
// ---------------------------------------------------------------------------
__global__ __launch_bounds__(256, 8) void pair_kernel(
    const float* __restrict__ ut, const float* __restrict__ vt,
    const float* __restrict__ a, const float* __restrict__ b,
    const float* __restrict__ W2, const float* __restrict__ b2,
    float* __restrict__ out) {
  const int t = threadIdx.x;
  const int L = t & 63;                 // lane -> output row
  const int w = t >> 6;                 // wave 0..3
  const int i = blockIdx.y * 64 + L;    // lane's row (coalesced along lanes)
  // wave-uniform j-base, certified uniform for the compiler -> s_load path
  const int j0 = __builtin_amdgcn_readfirstlane(blockIdx.x * 32 + w * 8);

  float acc[8] = {};
  for (int q = 0; q < 4; ++q) {         // 4 quarters of 16 h (VGPR <= 64)
    float uh[16];
#pragma unroll
    for (int k = 0; k < 16; ++k)        // coalesced b32: lane L -> ut[h][i]
      uh[k] = ut[(size_t)(q * 16 + k) * NN + i];
#pragma unroll
    for (int hh = 0; hh < 16; ++hh) {
      const int h = q * 16 + hh;
      const float wh = W2[h];                         // uniform -> s_load
      const float* vr = vt + (size_t)h * NN + j0;     // uniform base -> s_load
#pragma unroll
      for (int c = 0; c < 8; ++c) {
        acc[c] = fmaf(wh, fabsf(uh[hh] + vr[c]), acc[c]);  // v+s add, s*|v| fma
      }
    }
  }

  const float ai = a[i] + b2[0];
  float r[8];
#pragma unroll
  for (int c = 0; c < 8; ++c) {
    const float x = ai + b[j0 + c] + 0.5f * acc[c];   // b: uniform s_load
    r[c] = 1.0f / (1.0f + __expf(-x));
    if (i == j0 + c) r[c] = 0.0f;
  }
  float* orow = out + (size_t)i * NN + j0;
  *reinterpret_cast<float4*>(orow) = make_float4(r[0], r[1], r[2], r[3]);
  *reinterpret_cast<float4*>(orow + 4) = make_float4(r[4], r[5], r[6], r[7]);
}

extern "C" void kernel_launch(void* const* d_in, const int* in_sizes, int n_in,
                              void* d_out, int out_size, void* d_ws, size_t ws_size,
                              hipStream_t stream) {
  const float* z  = (const float*)d_in[0];
  const float* W1 = (const float*)d_in[1];
  const float* b1 = (const float*)d_in[2];
  const float* W2 = (const float*)d_in[3];
  const float* b2 = (const float*)d_in[4];
  float* out = (float*)d_out;

  float* ut = (float*)d_ws;               // [64][2048]  512 KB (transposed)
  float* vt = ut + (size_t)NN * HH;       // [64][2048]  512 KB (transposed)
  float* a  = vt + (size_t)NN * HH;       // [2048]      8 KB
  float* b  = a + NN;                     // [2048]      8 KB

  prep_kernel<<<NN / 8, 256, 0, stream>>>(z, W1, b1, W2, ut, vt, a, b);
  pair_kernel<<<dim3(NN / 32, NN / 64), 256, 0, stream>>>(ut, vt, a, b, W2, b2, out);
}